// Round 1
// baseline (721.728 us; speedup 1.0000x reference)
//
#include <hip/hip_runtime.h>
#include <stdint.h>

#define N_Q 784
#define DIM 512
#define N_M 65536
#define BN 64              // bank columns per chunk
#define NCHUNK (N_M / BN)  // 1024
#define QC 128             // query rows per inner chunk
#define NQC 7              // 7*128 = 896 (784 padded)
#define LCAND 4            // per-chunk top-L
#define RESCORE 16         // merged candidates rescored exactly

typedef float f32x4 __attribute__((ext_vector_type(4)));
typedef short bf16x8 __attribute__((ext_vector_type(8)));

__device__ __forceinline__ unsigned short f2bf(float x) {
    unsigned u = __float_as_uint(x);
    u += 0x7fffu + ((u >> 16) & 1u);
    return (unsigned short)(u >> 16);
}

__global__ void prep_query(const float* __restrict__ q, unsigned short* __restrict__ qb) {
    int i = (blockIdx.x * 256 + threadIdx.x) * 4;
    float4 v = *(const float4*)(q + i);
    ushort4 o;
    o.x = f2bf(v.x); o.y = f2bf(v.y); o.z = f2bf(v.z); o.w = f2bf(v.w);
    *(ushort4*)(qb + i) = o;
}

// 1024 workgroups; each stages a 64-col bank chunk (bf16, swizzled) in LDS,
// computes m2 per column, then loops 7 query chunks of 128 rows doing
// 16x16x32 bf16 MFMA and a per-chunk top-4 selection.
__global__ __launch_bounds__(512) void score_kernel(
    const float* __restrict__ bank,
    const unsigned short* __restrict__ qb,
    float2* __restrict__ cand)
{
    __shared__ __align__(16) char smem[76032];
    char*  bankL = smem;                       // [64][512] bf16 swizzled (65536 B)
    char*  qsl   = smem + 65536;               // union: qslice [128][32] bf16 / scorebuf [32][64] f32 (8192 B)
    float* m2p   = (float*)(smem + 73728);     // [64][8]
    float* m2    = (float*)(smem + 75776);     // [64]

    const int chunk = blockIdx.x;
    const int t = threadIdx.x;
    const int wave = t >> 6;
    const int lane = t & 63;

    // ---- stage bank chunk fp32 -> bf16 LDS (XOR-swizzled) ----
    const float* bsrc = bank + (size_t)chunk * BN * DIM;
    for (int i = 0; i < 16; ++i) {
        int e = i * 2048 + t * 4;
        float4 v = *(const float4*)(bsrc + e);
        int col = e >> 9;
        int k = e & 511;
        uint2 pk;
        pk.x = (unsigned)f2bf(v.x) | ((unsigned)f2bf(v.y) << 16);
        pk.y = (unsigned)f2bf(v.z) | ((unsigned)f2bf(v.w) << 16);
        int byte = col * 1024 + ((k * 2) ^ ((col & 7) << 4));
        *(uint2*)(bankL + byte) = pk;
    }
    __syncthreads();

    // ---- m2 per column from the LDS bf16 tile ----
    {
        int col = t >> 3, sub = t & 7;
        float s = 0.f;
        for (int k = sub * 64; k < sub * 64 + 64; k += 4) {
            int byte = col * 1024 + ((k * 2) ^ ((col & 7) << 4));
            uint2 pk = *(const uint2*)(bankL + byte);
            float x0 = __uint_as_float(pk.x << 16);
            float x1 = __uint_as_float(pk.x & 0xffff0000u);
            float x2 = __uint_as_float(pk.y << 16);
            float x3 = __uint_as_float(pk.y & 0xffff0000u);
            s += x0 * x0 + x1 * x1 + x2 * x2 + x3 * x3;
        }
        m2p[col * 8 + sub] = s;
    }
    __syncthreads();
    if (t < 64) {
        float s = 0.f;
        for (int j = 0; j < 8; ++j) s += m2p[t * 8 + j];
        m2[t] = s;
    }
    __syncthreads();

    const int rtp = wave & 3;   // row-tile pair -> rts {2rtp, 2rtp+1}
    const int ctp = wave >> 2;  // col half -> cols ctp*32 .. +31

    for (int qc = 0; qc < NQC; ++qc) {
        f32x4 acc[2][2] = {};
        for (int ks = 0; ks < 16; ++ks) {
            __syncthreads();  // previous consumers of qsl done
            {   // stage query slice [128 rows][32 k] bf16 (swizzled)
                int row = t >> 2;
                int kloc = (t & 3) * 8;
                int grow = qc * QC + row;
                uint4 v = make_uint4(0u, 0u, 0u, 0u);
                if (grow < N_Q)
                    v = *(const uint4*)(qb + (size_t)grow * DIM + ks * 32 + kloc);
                int byte = row * 64 + ((kloc * 2) ^ ((row & 3) << 4));
                *(uint4*)(qsl + byte) = v;
            }
            __syncthreads();
            bf16x8 a0, a1, b0, b1;
            {
                int kb = (lane >> 4) * 16;
                int r0 = (2 * rtp) * 16 + (lane & 15);
                int r1 = r0 + 16;
                a0 = *(const bf16x8*)(qsl + r0 * 64 + (kb ^ ((r0 & 3) << 4)));
                a1 = *(const bf16x8*)(qsl + r1 * 64 + (kb ^ ((r1 & 3) << 4)));
                int c0 = ctp * 32 + (lane & 15);
                int c1 = c0 + 16;
                b0 = *(const bf16x8*)(bankL + c0 * 1024 + ((ks * 64 + kb) ^ ((c0 & 7) << 4)));
                b1 = *(const bf16x8*)(bankL + c1 * 1024 + ((ks * 64 + kb) ^ ((c1 & 7) << 4)));
            }
            acc[0][0] = __builtin_amdgcn_mfma_f32_16x16x32_bf16(a0, b0, acc[0][0], 0, 0, 0);
            acc[0][1] = __builtin_amdgcn_mfma_f32_16x16x32_bf16(a0, b1, acc[0][1], 0, 0, 0);
            acc[1][0] = __builtin_amdgcn_mfma_f32_16x16x32_bf16(a1, b0, acc[1][0], 0, 0, 0);
            acc[1][1] = __builtin_amdgcn_mfma_f32_16x16x32_bf16(a1, b1, acc[1][1], 0, 0, 0);
        }
        __syncthreads();  // mfma reads of qsl done -> reuse as scorebuf
        float* sbuf = (float*)qsl;  // [2][16][64]
        for (int r = 0; r < 4; ++r) {
            if (rtp == r) {
                for (int rr = 0; rr < 2; ++rr)
                    for (int cc = 0; cc < 2; ++cc)
                        for (int reg = 0; reg < 4; ++reg) {
                            int row16 = (lane >> 4) * 4 + reg;
                            int colc = ctp * 32 + cc * 16 + (lane & 15);
                            sbuf[(rr * 16 + row16) * 64 + colc] = acc[rr][cc][reg];
                        }
            }
            __syncthreads();
            for (int rr = 0; rr < 4; ++rr) {
                int R = wave * 4 + rr;
                int rt = 2 * r + (R >> 4);
                int grow = qc * QC + rt * 16 + (R & 15);
                float adj = m2[lane] - 2.0f * sbuf[R * 64 + lane];
                float2 res[LCAND];
                for (int tt = 0; tt < LCAND; ++tt) {
                    float cv = adj; int ci = lane;
                    for (int off = 32; off; off >>= 1) {
                        float ov = __shfl_xor(cv, off);
                        int   oi = __shfl_xor(ci, off);
                        if (ov < cv || (ov == cv && oi < ci)) { cv = ov; ci = oi; }
                    }
                    if (lane == ci) adj = 3.0e38f;
                    res[tt] = make_float2(cv, __int_as_float(chunk * BN + ci));
                }
                if (lane == 0 && grow < N_Q) {
                    float2* dst = cand + ((size_t)grow * NCHUNK + chunk) * LCAND;
                    for (int tt = 0; tt < LCAND; ++tt) dst[tt] = res[tt];
                }
            }
            __syncthreads();
        }
    }
}

// One workgroup per query: merge 1024*4 chunk candidates -> approx top-16 ->
// exact fp64 rescore -> top-4 -> neighbor mean.
__global__ __launch_bounds__(256) void merge_kernel(
    const float* __restrict__ query, const float* __restrict__ bank,
    const float2* __restrict__ cand, float* __restrict__ nm)
{
    __shared__ float vals[4096];
    __shared__ int   idxs[4096];
    __shared__ float wv[4];
    __shared__ int   wj[4];
    __shared__ int   cidx[RESCORE];
    __shared__ double dsum[RESCORE][16];
    __shared__ int   sel4[4];

    int q = blockIdx.x, t = threadIdx.x;
    const float2* src = cand + (size_t)q * NCHUNK * LCAND;
    for (int j = t; j < 4096; j += 256) {
        float2 e = src[j];
        vals[j] = e.x;
        idxs[j] = __float_as_int(e.y);
    }
    __syncthreads();
    int wave = t >> 6, lane = t & 63;
    for (int it = 0; it < RESCORE; ++it) {
        float cv = 3.0e38f; int cj = 0;
        for (int j = t * 16; j < t * 16 + 16; ++j)
            if (vals[j] < cv) { cv = vals[j]; cj = j; }
        for (int off = 32; off; off >>= 1) {
            float ov = __shfl_xor(cv, off);
            int   oj = __shfl_xor(cj, off);
            if (ov < cv) { cv = ov; cj = oj; }
        }
        if (lane == 0) { wv[wave] = cv; wj[wave] = cj; }
        __syncthreads();
        if (t == 0) {
            float bv = wv[0]; int bj = wj[0];
            for (int w = 1; w < 4; ++w) if (wv[w] < bv) { bv = wv[w]; bj = wj[w]; }
            cidx[it] = idxs[bj];
            vals[bj] = 3.0e38f;
        }
        __syncthreads();
    }
    {   // exact fp64 rescore: 16 threads per candidate
        int c = t >> 4, g = t & 15;
        int m = cidx[c];
        const float* qr = query + (size_t)q * DIM;
        const float* mr = bank + (size_t)m * DIM;
        double s = 0.0;
        for (int d = g * 32; d < g * 32 + 32; ++d) {
            double diff = (double)qr[d] - (double)mr[d];
            s += diff * diff;
        }
        dsum[c][g] = s;
    }
    __syncthreads();
    if (t == 0) {
        double ex[RESCORE];
        for (int c = 0; c < RESCORE; ++c) {
            double s = 0.0;
            for (int g = 0; g < 16; ++g) s += dsum[c][g];
            ex[c] = s;
        }
        for (int k = 0; k < 4; ++k) {
            int best = 0; double bv = 1e300;
            for (int c = 0; c < RESCORE; ++c) if (ex[c] < bv) { bv = ex[c]; best = c; }
            sel4[k] = cidx[best];
            ex[best] = 1e300;
        }
    }
    __syncthreads();
    const float* b0 = bank + (size_t)sel4[0] * DIM;
    const float* b1 = bank + (size_t)sel4[1] * DIM;
    const float* b2 = bank + (size_t)sel4[2] * DIM;
    const float* b3 = bank + (size_t)sel4[3] * DIM;
    for (int d = t; d < DIM; d += 256)
        nm[(size_t)q * DIM + d] = 0.25f * (b0[d] + b1[d] + b2[d] + b3[d]);
}

__global__ __launch_bounds__(256) void conv_kernel(
    const float* __restrict__ query, const float* __restrict__ nm,
    const float* __restrict__ fw, const float* __restrict__ fb,
    float* __restrict__ out)
{
    __shared__ float red[256];
    int pix = blockIdx.x, t = threadIdx.x;
    int i = pix / 28, j = pix % 28;
    float acc = 0.f;
    for (int c = t; c < 1024; c += 256) {
        const float* wrow = fw + c * 9;
        for (int di = 0; di < 3; ++di) {
            int h = i + di - 1;
            if (h < 0 || h >= 28) continue;
            for (int dj = 0; dj < 3; ++dj) {
                int w = j + dj - 1;
                if (w < 0 || w >= 28) continue;
                int n = h * 28 + w;
                float x = (c < 512) ? query[(size_t)n * 512 + c]
                                    : nm[(size_t)n * 512 + (c - 512)];
                acc += x * wrow[di * 3 + dj];
            }
        }
    }
    red[t] = acc;
    __syncthreads();
    for (int s = 128; s; s >>= 1) {
        if (t < s) red[t] += red[t + s];
        __syncthreads();
    }
    if (t == 0) out[pix] = red[0] + fb[0];
}

extern "C" void kernel_launch(void* const* d_in, const int* in_sizes, int n_in,
                              void* d_out, int out_size, void* d_ws, size_t ws_size,
                              hipStream_t stream)
{
    const float* query = (const float*)d_in[0];
    const float* bank  = (const float*)d_in[1];
    const float* fw    = (const float*)d_in[2];
    const float* fb    = (const float*)d_in[3];
    float* out = (float*)d_out;

    char* ws = (char*)d_ws;
    unsigned short* qb = (unsigned short*)ws;                       // 784*512*2      = 802816 B
    float2* cand = (float2*)(ws + 802816);                          // 784*1024*4*8   = 25690112 B
    float*  nm   = (float*)(ws + 802816 + 25690112);                // 784*512*4      = 1605632 B

    prep_query<<<392, 256, 0, stream>>>(query, qb);
    score_kernel<<<NCHUNK, 512, 0, stream>>>(bank, qb, cand);
    merge_kernel<<<N_Q, 256, 0, stream>>>(query, bank, cand, nm);
    conv_kernel<<<N_Q, 256, 0, stream>>>(query, nm, fw, fb, out);
}

// Round 2
// 332.808 us; speedup vs baseline: 2.1686x; 2.1686x over previous
//
#include <hip/hip_runtime.h>
#include <stdint.h>

#define DIMS 512
#define NQ 784
#define NQPAD 896          // 7 * 128 padded query rows
#define NM 65536
#define BN 64              // bank rows per chunk
#define NCHUNK 1024
#define QC 128             // query rows per qc tile
#define NQC 7
#define ROWSTRIDE 1040     // bank row stride in LDS bytes (1024 + 16 pad -> 2-way-only conflicts)
#define RESCORE 16

typedef float f32x4 __attribute__((ext_vector_type(4)));
typedef short bf16x8 __attribute__((ext_vector_type(8)));

__device__ __forceinline__ unsigned short f2bf(float x) {
    unsigned u = __float_as_uint(x);
    u += 0x7fffu + ((u >> 16) & 1u);
    return (unsigned short)(u >> 16);
}

__device__ __forceinline__ unsigned umn(unsigned a, unsigned b) { return a < b ? a : b; }
__device__ __forceinline__ unsigned umx(unsigned a, unsigned b) { return a > b ? a : b; }

__global__ __launch_bounds__(256) void prep_query(const float* __restrict__ q,
                                                  unsigned short* __restrict__ qbuf) {
    int i = (blockIdx.x * 256 + threadIdx.x) * 4;
    int row = i >> 9;
    ushort4 o = make_ushort4(0, 0, 0, 0);
    if (row < NQ) {
        float4 v = *(const float4*)(q + i);
        o.x = f2bf(v.x); o.y = f2bf(v.y); o.z = f2bf(v.z); o.w = f2bf(v.w);
    }
    *(ushort4*)(qbuf + i) = o;
}

// One WG (4 waves) per 64-row bank chunk. Bank chunk resident in LDS (bf16,
// padded stride). C^T orientation: A=bank, B=query (global, L2-resident).
// Zero barriers in the qc loop; per-lane streaming top-2 packed selection.
__global__ __launch_bounds__(256) void score_kernel(
    const float* __restrict__ bank,
    const unsigned short* __restrict__ qb,
    uint2* __restrict__ cand)
{
    __shared__ __align__(16) char bankL[BN * ROWSTRIDE];   // 66560 B
    __shared__ float m2p[BN][4];
    __shared__ float m2s[BN];

    const int chunk = blockIdx.x;
    const int t = threadIdx.x;
    const int wave = t >> 6;
    const int lane = t & 63;

    // ---- stage bank chunk fp32 -> bf16 LDS; fused m2 partials ----
    {
        const int row = t >> 2, kseg = t & 3;
        const float* src = bank + ((size_t)(chunk * BN + row)) * DIMS + kseg * 128;
        char* dst = bankL + row * ROWSTRIDE + kseg * 256;
        float ss = 0.f;
        #pragma unroll
        for (int i = 0; i < 32; ++i) {
            float4 v = *(const float4*)(src + i * 4);
            ss += v.x * v.x + v.y * v.y + v.z * v.z + v.w * v.w;
            uint2 pk;
            pk.x = (unsigned)f2bf(v.x) | ((unsigned)f2bf(v.y) << 16);
            pk.y = (unsigned)f2bf(v.z) | ((unsigned)f2bf(v.w) << 16);
            *(uint2*)(dst + i * 8) = pk;
        }
        m2p[row][kseg] = ss;
    }
    __syncthreads();
    if (t < BN) m2s[t] = m2p[t][0] + m2p[t][1] + m2p[t][2] + m2p[t][3] + 2048.0f;
    __syncthreads();

    // per-lane m2 (+offset) for its 16 in-lane bank rows
    float m2r[4][4];
    #pragma unroll
    for (int m = 0; m < 4; ++m)
        #pragma unroll
        for (int r = 0; r < 4; ++r)
            m2r[m][r] = m2s[m * 16 + ((lane >> 4) << 2) + r];

    const char* abase[4];
    #pragma unroll
    for (int m = 0; m < 4; ++m)
        abase[m] = bankL + (m * 16 + (lane & 15)) * ROWSTRIDE + ((lane >> 4) << 4);

    for (int qc = 0; qc < NQC; ++qc) {
        const int qrow0 = qc * QC + wave * 32 + (lane & 15);
        const unsigned short* bptr0 = qb + (size_t)qrow0 * DIMS + ((lane >> 4) << 3);
        const unsigned short* bptr1 = bptr0 + 16 * DIMS;

        f32x4 acc[4][2] = {};
        #pragma unroll
        for (int ks = 0; ks < 16; ++ks) {
            bf16x8 b0 = *(const bf16x8*)(bptr0 + ks * 32);
            bf16x8 b1 = *(const bf16x8*)(bptr1 + ks * 32);
            #pragma unroll
            for (int m = 0; m < 4; ++m) {
                bf16x8 a = *(const bf16x8*)(abase[m] + ks * 64);
                acc[m][0] = __builtin_amdgcn_mfma_f32_16x16x32_bf16(a, b0, acc[m][0], 0, 0, 0);
                acc[m][1] = __builtin_amdgcn_mfma_f32_16x16x32_bf16(a, b1, acc[m][1], 0, 0, 0);
            }
        }

        // ---- in-register top-2 per (query row, chunk) ----
        #pragma unroll
        for (int n = 0; n < 2; ++n) {
            unsigned v1 = 0xFFFFFFFFu, v2 = 0xFFFFFFFFu;
            #pragma unroll
            for (int m = 0; m < 4; ++m)
                #pragma unroll
                for (int r = 0; r < 4; ++r) {
                    float s = fmaf(-2.0f, acc[m][n][r], m2r[m][r]);
                    unsigned u = (__float_as_uint(s) & ~63u) |
                                 (unsigned)(m * 16 + ((lane >> 4) << 2) + r);
                    unsigned nv2 = umn(v2, umx(v1, u));
                    v1 = umn(v1, u);
                    v2 = nv2;
                }
            #pragma unroll
            for (int off = 16; off <= 32; off <<= 1) {
                unsigned o1 = (unsigned)__shfl_xor((int)v1, off);
                unsigned o2 = (unsigned)__shfl_xor((int)v2, off);
                unsigned nv2 = umn(umn(v2, o2), umx(v1, o1));
                v1 = umn(v1, o1);
                v2 = nv2;
            }
            if (lane < 16) {
                int qrow = qc * QC + wave * 32 + n * 16 + lane;
                cand[(size_t)chunk * NQPAD + qrow] = make_uint2(v1, v2);
            }
        }
    }
}

// One WG per query row: merge 1024*2 packed candidates -> top-16 -> exact
// fp64 rescore -> top-4 -> neighbor mean.
__global__ __launch_bounds__(256) void merge_kernel(
    const float* __restrict__ query, const float* __restrict__ bank,
    const unsigned* __restrict__ cand, float* __restrict__ nm)
{
    __shared__ unsigned vals[2048];
    __shared__ unsigned wmin[4];
    __shared__ unsigned gmS;
    __shared__ int winnerS;
    __shared__ int cidx[RESCORE];
    __shared__ double dsum[RESCORE][16];
    __shared__ int sel4[4];

    const int row = blockIdx.x, t = threadIdx.x;
    const int wave = t >> 6, lane = t & 63;

    for (int c = t; c < NCHUNK; c += 256) {
        uint2 e = *(const uint2*)(cand + ((size_t)c * NQPAD + row) * 2);
        vals[c * 2] = e.x;
        vals[c * 2 + 1] = e.y;
    }
    __syncthreads();

    for (int it = 0; it < RESCORE; ++it) {
        unsigned lmin = 0xFFFFFFFFu; int lj = 0;
        #pragma unroll
        for (int k = 0; k < 8; ++k) {
            int j = t * 8 + k;
            if (vals[j] < lmin) { lmin = vals[j]; lj = j; }
        }
        unsigned wm = lmin;
        for (int off = 32; off; off >>= 1) wm = umn(wm, (unsigned)__shfl_xor((int)wm, off));
        if (lane == 0) wmin[wave] = wm;
        __syncthreads();
        if (t == 0) {
            gmS = umn(umn(wmin[0], wmin[1]), umn(wmin[2], wmin[3]));
            winnerS = 1 << 30;
        }
        __syncthreads();
        if (lmin == gmS) atomicMin(&winnerS, t);
        __syncthreads();
        if (t == winnerS) {
            cidx[it] = (lj >> 1) * 64 + (int)(lmin & 63u);
            vals[lj] = 0xFFFFFFFFu;
        }
        __syncthreads();
    }

    {   // exact fp64 rescore: 16 threads per candidate
        int c = t >> 4, g = t & 15;
        int m = cidx[c];
        const float* qr = query + (size_t)row * DIMS;
        const float* mr = bank + (size_t)m * DIMS;
        double s = 0.0;
        for (int d = g * 32; d < g * 32 + 32; ++d) {
            double diff = (double)qr[d] - (double)mr[d];
            s += diff * diff;
        }
        dsum[c][g] = s;
    }
    __syncthreads();
    if (t == 0) {
        double ex[RESCORE];
        for (int c = 0; c < RESCORE; ++c) {
            double s = 0.0;
            for (int g = 0; g < 16; ++g) s += dsum[c][g];
            ex[c] = s;
        }
        for (int k = 0; k < 4; ++k) {
            int best = -1; double bv = 1e300; int bidx = 1 << 30;
            for (int c = 0; c < RESCORE; ++c)
                if (ex[c] < bv || (ex[c] == bv && cidx[c] < bidx)) {
                    bv = ex[c]; best = c; bidx = cidx[c];
                }
            sel4[k] = cidx[best];
            ex[best] = 1e300;
        }
    }
    __syncthreads();
    const float* b0 = bank + (size_t)sel4[0] * DIMS;
    const float* b1 = bank + (size_t)sel4[1] * DIMS;
    const float* b2 = bank + (size_t)sel4[2] * DIMS;
    const float* b3 = bank + (size_t)sel4[3] * DIMS;
    for (int d = t; d < DIMS; d += 256)
        nm[(size_t)row * DIMS + d] = 0.25f * (b0[d] + b1[d] + b2[d] + b3[d]);
}

__global__ __launch_bounds__(256) void conv_kernel(
    const float* __restrict__ query, const float* __restrict__ nm,
    const float* __restrict__ fw, const float* __restrict__ fb,
    float* __restrict__ out)
{
    __shared__ float red[256];
    int pix = blockIdx.x, t = threadIdx.x;
    int i = pix / 28, j = pix % 28;
    float acc = 0.f;
    for (int c = t; c < 1024; c += 256) {
        const float* wrow = fw + c * 9;
        for (int di = 0; di < 3; ++di) {
            int h = i + di - 1;
            if (h < 0 || h >= 28) continue;
            for (int dj = 0; dj < 3; ++dj) {
                int w = j + dj - 1;
                if (w < 0 || w >= 28) continue;
                int n = h * 28 + w;
                float x = (c < 512) ? query[(size_t)n * 512 + c]
                                    : nm[(size_t)n * 512 + (c - 512)];
                acc += x * wrow[di * 3 + dj];
            }
        }
    }
    red[t] = acc;
    __syncthreads();
    for (int s = 128; s; s >>= 1) {
        if (t < s) red[t] += red[t + s];
        __syncthreads();
    }
    if (t == 0) out[pix] = red[0] + fb[0];
}

extern "C" void kernel_launch(void* const* d_in, const int* in_sizes, int n_in,
                              void* d_out, int out_size, void* d_ws, size_t ws_size,
                              hipStream_t stream)
{
    const float* query = (const float*)d_in[0];
    const float* bank  = (const float*)d_in[1];
    const float* fw    = (const float*)d_in[2];
    const float* fb    = (const float*)d_in[3];
    float* out = (float*)d_out;

    char* ws = (char*)d_ws;
    unsigned short* qbuf = (unsigned short*)ws;            // 896*512*2   =   917504 B
    uint2* cand = (uint2*)(ws + 917504);                   // 1024*896*8  =  7340032 B
    float* nm   = (float*)(ws + 917504 + 7340032);         // 784*512*4   =  1605632 B

    prep_query<<<NQPAD * DIMS / 1024, 256, 0, stream>>>(query, qbuf);
    score_kernel<<<NCHUNK, 256, 0, stream>>>(bank, qbuf, cand);
    merge_kernel<<<NQ, 256, 0, stream>>>(query, bank, (const unsigned*)cand, nm);
    conv_kernel<<<NQ, 256, 0, stream>>>(query, nm, fw, fb, out);
}

// Round 3
// 217.266 us; speedup vs baseline: 3.3219x; 1.5318x over previous
//
#include <hip/hip_runtime.h>
#include <hip/hip_bf16.h>
#include <stdint.h>

#define DIMS 512
#define NQ 784
#define NQPAD 896          // padded query rows (14 tiles of 64)
#define NM 65536
#define NTILE 14           // 896 / 64 query-column tiles
#define NGROUP 2048        // 256 WG * 8 waves (row groups of 32)
#define RESCORE 16

typedef float f32x4 __attribute__((ext_vector_type(4)));
typedef short bf16x8 __attribute__((ext_vector_type(8)));

__device__ __forceinline__ unsigned short f2bf(float x) {
    unsigned u = __float_as_uint(x);
    u += 0x7fffu + ((u >> 16) & 1u);
    return (unsigned short)(u >> 16);
}
__device__ __forceinline__ unsigned umn(unsigned a, unsigned b) { return a < b ? a : b; }
__device__ __forceinline__ unsigned umx(unsigned a, unsigned b) { return a > b ? a : b; }

__global__ __launch_bounds__(256) void prep_query(const float* __restrict__ q,
                                                  unsigned short* __restrict__ qbuf) {
    int i = (blockIdx.x * 256 + threadIdx.x) * 4;
    int row = i >> 9;
    ushort4 o = make_ushort4(0, 0, 0, 0);
    if (row < NQ) {
        float4 v = *(const float4*)(q + i);
        o.x = f2bf(v.x); o.y = f2bf(v.y); o.z = f2bf(v.z); o.w = f2bf(v.w);
    }
    *(ushort4*)(qbuf + i) = o;
}

// 256 WGs x 8 waves. Each wave holds 32 bank rows (full K=512) as MFMA
// A-fragments in registers. Query tiles (64 cols x 512 k, bf16) stream
// through double-buffered LDS staged via pre-swizzled global_load_lds.
// Per-wave in-register top-2 per (query col, 32-row group).
__global__ __launch_bounds__(512, 2) void score_kernel(
    const float* __restrict__ bank,
    const unsigned short* __restrict__ qbuf,
    uint2* __restrict__ cand)
{
    __shared__ __align__(16) char bt[2][65536];
    __shared__ float m2s[256];

    const int wg = blockIdx.x;
    const int t = threadIdx.x;
    const int v = t >> 6;         // wave 0..7
    const int lane = t & 63;
    const int lo = lane & 15;
    const int kg = lane >> 4;     // 0..3

    // ---- A-load: 32 bank rows/wave, fp32 -> bf16 fragments in registers ----
    bf16x8 areg[2][16];
    float m2p[2];
    #pragma unroll
    for (int m = 0; m < 2; ++m) {
        const float* rp = bank + ((size_t)(wg * 256 + v * 32 + m * 16 + lo)) * DIMS + kg * 8;
        float ss = 0.f;
        #pragma unroll
        for (int ks = 0; ks < 16; ++ks) {
            float4 x = *(const float4*)(rp + ks * 32);
            float4 y = *(const float4*)(rp + ks * 32 + 4);
            ss += x.x * x.x + x.y * x.y + x.z * x.z + x.w * x.w;
            ss += y.x * y.x + y.y * y.y + y.z * y.z + y.w * y.w;
            union { bf16x8 v8; unsigned u[4]; } fr;
            __hip_bfloat162 h0 = __float22bfloat162_rn(make_float2(x.x, x.y));
            __hip_bfloat162 h1 = __float22bfloat162_rn(make_float2(x.z, x.w));
            __hip_bfloat162 h2 = __float22bfloat162_rn(make_float2(y.x, y.y));
            __hip_bfloat162 h3 = __float22bfloat162_rn(make_float2(y.z, y.w));
            fr.u[0] = *reinterpret_cast<unsigned*>(&h0);
            fr.u[1] = *reinterpret_cast<unsigned*>(&h1);
            fr.u[2] = *reinterpret_cast<unsigned*>(&h2);
            fr.u[3] = *reinterpret_cast<unsigned*>(&h3);
            areg[m][ks] = fr.v8;
        }
        m2p[m] = ss;
    }
    #pragma unroll
    for (int m = 0; m < 2; ++m) {
        m2p[m] += __shfl_xor(m2p[m], 16);
        m2p[m] += __shfl_xor(m2p[m], 32);
    }
    if (lane < 16) {
        m2s[v * 32 + lane] = m2p[0];
        m2s[v * 32 + 16 + lane] = m2p[1];
    }
    __syncthreads();
    // acc seed: -(1024 + m2[row])/2 for this lane's C rows (row = m*16 + kg*4 + j)
    f32x4 seed0, seed1;
    #pragma unroll
    for (int j = 0; j < 4; ++j) {
        seed0[j] = -0.5f * (1024.0f + m2s[v * 32 + kg * 4 + j]);
        seed1[j] = -0.5f * (1024.0f + m2s[v * 32 + 16 + kg * 4 + j]);
    }
    __syncthreads();

#define STAGE(buf, tile)                                                                 \
    do {                                                                                 \
        _Pragma("unroll")                                                                \
        for (int j = 0; j < 8; ++j) {                                                    \
            int col = v * 8 + j;                                                         \
            const unsigned short* src =                                                  \
                qbuf + ((size_t)((tile) * 64 + col)) * DIMS + ((lane ^ (col & 3)) * 8);  \
            __builtin_amdgcn_global_load_lds(                                            \
                (const __attribute__((address_space(1))) unsigned*)src,                  \
                (__attribute__((address_space(3))) unsigned*)(&bt[buf][col * 1024]),     \
                16, 0, 0);                                                               \
        }                                                                                \
    } while (0)

    STAGE(0, 0);
    asm volatile("s_waitcnt vmcnt(0)" ::: "memory");
    __syncthreads();

    const int swz = (kg ^ (lo & 3)) * 16;   // 2-bit XOR swizzle, folds into base

    #pragma unroll 1
    for (int tile = 0; tile < NTILE; ++tile) {
        const int cur = tile & 1;
        if (tile + 1 < NTILE) STAGE(cur ^ 1, tile + 1);

        const char* B = &bt[cur][0];
        #pragma unroll
        for (int ntp = 0; ntp < 2; ++ntp) {
            const char* pb0 = B + (ntp * 32 + lo) * 1024 + swz;
            const char* pb1 = pb0 + 16 * 1024;
            f32x4 a00 = seed0, a01 = seed1, a10 = seed0, a11 = seed1;
            #pragma unroll
            for (int ks = 0; ks < 16; ++ks) {
                bf16x8 b0 = *(const bf16x8*)(pb0 + ks * 64);
                bf16x8 b1 = *(const bf16x8*)(pb1 + ks * 64);
                a00 = __builtin_amdgcn_mfma_f32_16x16x32_bf16(areg[0][ks], b0, a00, 0, 0, 0);
                a01 = __builtin_amdgcn_mfma_f32_16x16x32_bf16(areg[1][ks], b0, a01, 0, 0, 0);
                a10 = __builtin_amdgcn_mfma_f32_16x16x32_bf16(areg[0][ks], b1, a10, 0, 0, 0);
                a11 = __builtin_amdgcn_mfma_f32_16x16x32_bf16(areg[1][ks], b1, a11, 0, 0, 0);
            }
            // ---- top-2 per query col over this wave's 32 rows ----
            #pragma unroll
            for (int n = 0; n < 2; ++n) {
                unsigned v1 = 0xFFFFFFFFu, v2 = 0xFFFFFFFFu;
                const f32x4& am0 = n ? a10 : a00;
                const f32x4& am1 = n ? a11 : a01;
                #pragma unroll
                for (int j = 0; j < 4; ++j) {
                    float s0 = -2.0f * am0[j];
                    unsigned u0 = (__float_as_uint(s0) & ~31u) | (unsigned)(kg * 4 + j);
                    unsigned t0 = umx(v1, u0);
                    v1 = umn(v1, u0);
                    v2 = umn(v2, t0);
                    float s1 = -2.0f * am1[j];
                    unsigned u1 = (__float_as_uint(s1) & ~31u) | (unsigned)(16 + kg * 4 + j);
                    unsigned t1 = umx(v1, u1);
                    v1 = umn(v1, u1);
                    v2 = umn(v2, t1);
                }
                #pragma unroll
                for (int off = 16; off <= 32; off <<= 1) {
                    unsigned o1 = (unsigned)__shfl_xor((int)v1, off);
                    unsigned o2 = (unsigned)__shfl_xor((int)v2, off);
                    unsigned mx = umx(v1, o1);
                    v1 = umn(v1, o1);
                    v2 = umn(umn(v2, o2), mx);
                }
                if (lane < 16) {
                    int col = tile * 64 + ntp * 32 + n * 16 + lane;
                    cand[(size_t)(wg * 8 + v) * NQPAD + col] = make_uint2(v1, v2);
                }
            }
        }
        asm volatile("s_waitcnt vmcnt(0)" ::: "memory");
        __syncthreads();
    }
#undef STAGE
}

// One WG per query row: merge 2048 groups x top-2 -> top-16 -> exact fp64
// rescore -> top-4 -> neighbor mean.
__global__ __launch_bounds__(256) void merge_kernel(
    const float* __restrict__ query, const float* __restrict__ bank,
    const uint2* __restrict__ cand, float* __restrict__ nm)
{
    __shared__ unsigned vals[4096];
    __shared__ unsigned wmin[4];
    __shared__ unsigned gmS;
    __shared__ int winnerS;
    __shared__ int cidx[RESCORE];
    __shared__ double dsum[RESCORE][16];
    __shared__ int sel4[4];

    const int row = blockIdx.x, t = threadIdx.x;
    const int wave = t >> 6, lane = t & 63;

    for (int g = t; g < NGROUP; g += 256) {
        uint2 e = cand[(size_t)g * NQPAD + row];
        vals[g * 2] = e.x;
        vals[g * 2 + 1] = e.y;
    }
    __syncthreads();

    for (int it = 0; it < RESCORE; ++it) {
        unsigned lmin = 0xFFFFFFFFu; int lj = 0;
        #pragma unroll
        for (int k = 0; k < 16; ++k) {
            int j = t * 16 + k;
            if (vals[j] < lmin) { lmin = vals[j]; lj = j; }
        }
        unsigned wm = lmin;
        for (int off = 32; off; off >>= 1) wm = umn(wm, (unsigned)__shfl_xor((int)wm, off));
        if (lane == 0) wmin[wave] = wm;
        __syncthreads();
        if (t == 0) {
            gmS = umn(umn(wmin[0], wmin[1]), umn(wmin[2], wmin[3]));
            winnerS = 1 << 30;
        }
        __syncthreads();
        if (lmin == gmS) atomicMin(&winnerS, t);
        __syncthreads();
        if (t == winnerS) {
            cidx[it] = (lj >> 1) * 32 + (int)(lmin & 31u);
            vals[lj] = 0xFFFFFFFFu;
        }
        __syncthreads();
    }

    {   // exact fp64 rescore: 16 threads per candidate
        int c = t >> 4, g = t & 15;
        int m = cidx[c];
        const float* qr = query + (size_t)row * DIMS;
        const float* mr = bank + (size_t)m * DIMS;
        double s = 0.0;
        for (int d = g * 32; d < g * 32 + 32; ++d) {
            double diff = (double)qr[d] - (double)mr[d];
            s += diff * diff;
        }
        dsum[c][g] = s;
    }
    __syncthreads();
    if (t == 0) {
        double ex[RESCORE];
        for (int c = 0; c < RESCORE; ++c) {
            double s = 0.0;
            for (int g = 0; g < 16; ++g) s += dsum[c][g];
            ex[c] = s;
        }
        for (int k = 0; k < 4; ++k) {
            int best = 0; double bv = 1e300; int bidx = 1 << 30;
            for (int c = 0; c < RESCORE; ++c)
                if (ex[c] < bv || (ex[c] == bv && cidx[c] < bidx)) {
                    bv = ex[c]; best = c; bidx = cidx[c];
                }
            sel4[k] = cidx[best];
            ex[best] = 1e300;
        }
    }
    __syncthreads();
    const float* b0 = bank + (size_t)sel4[0] * DIMS;
    const float* b1 = bank + (size_t)sel4[1] * DIMS;
    const float* b2 = bank + (size_t)sel4[2] * DIMS;
    const float* b3 = bank + (size_t)sel4[3] * DIMS;
    for (int d = t; d < DIMS; d += 256)
        nm[(size_t)row * DIMS + d] = 0.25f * (b0[d] + b1[d] + b2[d] + b3[d]);
}

__global__ __launch_bounds__(256) void conv_kernel(
    const float* __restrict__ query, const float* __restrict__ nm,
    const float* __restrict__ fw, const float* __restrict__ fb,
    float* __restrict__ out)
{
    __shared__ float red[256];
    int pix = blockIdx.x, t = threadIdx.x;
    int i = pix / 28, j = pix % 28;
    float acc = 0.f;
    for (int c = t; c < 1024; c += 256) {
        const float* wrow = fw + c * 9;
        for (int di = 0; di < 3; ++di) {
            int h = i + di - 1;
            if (h < 0 || h >= 28) continue;
            for (int dj = 0; dj < 3; ++dj) {
                int w = j + dj - 1;
                if (w < 0 || w >= 28) continue;
                int n = h * 28 + w;
                float x = (c < 512) ? query[(size_t)n * 512 + c]
                                    : nm[(size_t)n * 512 + (c - 512)];
                acc += x * wrow[di * 3 + dj];
            }
        }
    }
    red[t] = acc;
    __syncthreads();
    for (int s = 128; s; s >>= 1) {
        if (t < s) red[t] += red[t + s];
        __syncthreads();
    }
    if (t == 0) out[pix] = red[0] + fb[0];
}

extern "C" void kernel_launch(void* const* d_in, const int* in_sizes, int n_in,
                              void* d_out, int out_size, void* d_ws, size_t ws_size,
                              hipStream_t stream)
{
    const float* query = (const float*)d_in[0];
    const float* bank  = (const float*)d_in[1];
    const float* fw    = (const float*)d_in[2];
    const float* fb    = (const float*)d_in[3];
    float* out = (float*)d_out;

    char* ws = (char*)d_ws;
    unsigned short* qbuf = (unsigned short*)ws;            // 896*512*2    =   917504 B
    uint2* cand = (uint2*)(ws + 917504);                   // 2048*896*8   = 14680064 B
    float* nm   = (float*)(ws + 917504 + 14680064);        // 784*512*4    =  1605632 B

    prep_query<<<NQPAD * DIMS / 1024, 256, 0, stream>>>(query, qbuf);
    score_kernel<<<256, 512, 0, stream>>>(bank, qbuf, cand);
    merge_kernel<<<NQ, 256, 0, stream>>>(query, bank, cand, nm);
    conv_kernel<<<NQ, 256, 0, stream>>>(query, nm, fw, fb, out);
}

// Round 4
// 128.633 us; speedup vs baseline: 5.6107x; 1.6890x over previous
//
#include <hip/hip_runtime.h>
#include <hip/hip_bf16.h>
#include <stdint.h>

#define DIMS 512
#define NQ 784
#define QPAD 832           // 13 tiles of 64 query columns
#define NM 65536
#define NTILE 13
#define NGROUP 2048        // 256 WG * 8 waves (row groups of 32)
#define RESCORE 16
#define COLSTRIDE 1040     // LDS bytes per query column: 1024 + 16 -> 2-way-only banks

typedef float f32x4 __attribute__((ext_vector_type(4)));
typedef short bf16x8 __attribute__((ext_vector_type(8)));

__device__ __forceinline__ unsigned short f2bf(float x) {
    unsigned u = __float_as_uint(x);
    u += 0x7fffu + ((u >> 16) & 1u);
    return (unsigned short)(u >> 16);
}
__device__ __forceinline__ unsigned umn(unsigned a, unsigned b) { return a < b ? a : b; }
__device__ __forceinline__ unsigned umx(unsigned a, unsigned b) { return a > b ? a : b; }

__global__ __launch_bounds__(256) void prep_query(const float* __restrict__ q,
                                                  unsigned short* __restrict__ qbuf) {
    int i = (blockIdx.x * 256 + threadIdx.x) * 4;
    int row = i >> 9;
    ushort4 o = make_ushort4(0, 0, 0, 0);
    if (row < NQ) {
        float4 v = *(const float4*)(q + i);
        o.x = f2bf(v.x); o.y = f2bf(v.y); o.z = f2bf(v.z); o.w = f2bf(v.w);
    }
    *(ushort4*)(qbuf + i) = o;
}

// 256 WGs x 8 waves. Each wave holds 32 bank rows (full K=512) as MFMA
// A-fragments in registers. Query tiles (64 cols x 512 k, bf16) stream
// through double-buffered LDS (column stride 1040B -> conflict-free reads),
// staged via global_load_lds. Per-wave in-register top-2 per (col, group).
__global__ __launch_bounds__(512, 1) void score_kernel(
    const float* __restrict__ bank,
    const unsigned short* __restrict__ qbuf,
    uint2* __restrict__ cand)
{
    __shared__ __align__(16) char bt[2][64 * COLSTRIDE];   // 133120 B
    __shared__ float m2s[256];

    const int wg = blockIdx.x;
    const int t = threadIdx.x;
    const int v = t >> 6;         // wave 0..7
    const int lane = t & 63;
    const int lo = lane & 15;
    const int kg = lane >> 4;     // 0..3

#define STAGE(buf, tile)                                                                  \
    do {                                                                                  \
        _Pragma("unroll")                                                                 \
        for (int j = 0; j < 8; ++j) {                                                     \
            const int col = v * 8 + j;                                                    \
            const unsigned short* src =                                                   \
                qbuf + ((size_t)((tile) * 64 + col)) * DIMS + lane * 8;                   \
            __builtin_amdgcn_global_load_lds(                                             \
                (const __attribute__((address_space(1))) unsigned*)src,                   \
                (__attribute__((address_space(3))) unsigned*)(&bt[buf][col * COLSTRIDE]), \
                16, 0, 0);                                                                \
        }                                                                                 \
    } while (0)

    // issue tile-0 stage first so it overlaps the A-load
    STAGE(0, 0);

    // ---- A-load: 32 bank rows/wave, fp32 -> bf16 fragments in registers ----
    bf16x8 areg[2][16];
    float m2p[2];
    #pragma unroll
    for (int m = 0; m < 2; ++m) {
        const float* rp = bank + ((size_t)(wg * 256 + v * 32 + m * 16 + lo)) * DIMS + kg * 8;
        float ss = 0.f;
        #pragma unroll
        for (int ks = 0; ks < 16; ++ks) {
            float4 x = *(const float4*)(rp + ks * 32);
            float4 y = *(const float4*)(rp + ks * 32 + 4);
            ss += x.x * x.x + x.y * x.y + x.z * x.z + x.w * x.w;
            ss += y.x * y.x + y.y * y.y + y.z * y.z + y.w * y.w;
            union { bf16x8 v8; unsigned u[4]; } fr;
            __hip_bfloat162 h0 = __float22bfloat162_rn(make_float2(x.x, x.y));
            __hip_bfloat162 h1 = __float22bfloat162_rn(make_float2(x.z, x.w));
            __hip_bfloat162 h2 = __float22bfloat162_rn(make_float2(y.x, y.y));
            __hip_bfloat162 h3 = __float22bfloat162_rn(make_float2(y.z, y.w));
            fr.u[0] = *reinterpret_cast<unsigned*>(&h0);
            fr.u[1] = *reinterpret_cast<unsigned*>(&h1);
            fr.u[2] = *reinterpret_cast<unsigned*>(&h2);
            fr.u[3] = *reinterpret_cast<unsigned*>(&h3);
            areg[m][ks] = fr.v8;
        }
        m2p[m] = ss;
    }
    #pragma unroll
    for (int m = 0; m < 2; ++m) {
        m2p[m] += __shfl_xor(m2p[m], 16);
        m2p[m] += __shfl_xor(m2p[m], 32);
    }
    if (lane < 16) {
        m2s[v * 32 + lane] = m2p[0];
        m2s[v * 32 + 16 + lane] = m2p[1];
    }
    __syncthreads();
    // acc seed: -(1024 + m2[row])/2; score = -2*acc = 1024 + m2 - 2*q.m > 0
    f32x4 seed0, seed1;
    #pragma unroll
    for (int j = 0; j < 4; ++j) {
        seed0[j] = -0.5f * (1024.0f + m2s[v * 32 + kg * 4 + j]);
        seed1[j] = -0.5f * (1024.0f + m2s[v * 32 + 16 + kg * 4 + j]);
    }

    asm volatile("s_waitcnt vmcnt(0)" ::: "memory");
    __syncthreads();

    #pragma unroll 1
    for (int tile = 0; tile < NTILE; ++tile) {
        const int cur = tile & 1;
        if (tile + 1 < NTILE) STAGE(cur ^ 1, tile + 1);

        const char* B = &bt[cur][0];
        const int ntpEnd = (tile == NTILE - 1) ? 1 : 2;   // last tile: cols 768..799 only
        #pragma unroll 1
        for (int ntp = 0; ntp < ntpEnd; ++ntp) {
            const char* pb0 = B + (ntp * 32 + lo) * COLSTRIDE + kg * 16;
            const char* pb1 = pb0 + 16 * COLSTRIDE;
            f32x4 a00 = seed0, a01 = seed1, a10 = seed0, a11 = seed1;
            #pragma unroll
            for (int ks = 0; ks < 16; ++ks) {
                bf16x8 b0 = *(const bf16x8*)(pb0 + ks * 64);
                bf16x8 b1 = *(const bf16x8*)(pb1 + ks * 64);
                a00 = __builtin_amdgcn_mfma_f32_16x16x32_bf16(areg[0][ks], b0, a00, 0, 0, 0);
                a01 = __builtin_amdgcn_mfma_f32_16x16x32_bf16(areg[1][ks], b0, a01, 0, 0, 0);
                a10 = __builtin_amdgcn_mfma_f32_16x16x32_bf16(areg[0][ks], b1, a10, 0, 0, 0);
                a11 = __builtin_amdgcn_mfma_f32_16x16x32_bf16(areg[1][ks], b1, a11, 0, 0, 0);
            }
            // ---- top-2 per query col over this wave's 32 rows ----
            #pragma unroll
            for (int n = 0; n < 2; ++n) {
                unsigned v1 = 0xFFFFFFFFu, v2 = 0xFFFFFFFFu;
                const f32x4& am0 = n ? a10 : a00;
                const f32x4& am1 = n ? a11 : a01;
                #pragma unroll
                for (int j = 0; j < 4; ++j) {
                    float s0 = -2.0f * am0[j];
                    unsigned u0 = (__float_as_uint(s0) & ~31u) | (unsigned)(kg * 4 + j);
                    unsigned t0 = umx(v1, u0);
                    v1 = umn(v1, u0);
                    v2 = umn(v2, t0);
                    float s1 = -2.0f * am1[j];
                    unsigned u1 = (__float_as_uint(s1) & ~31u) | (unsigned)(16 + kg * 4 + j);
                    unsigned t1 = umx(v1, u1);
                    v1 = umn(v1, u1);
                    v2 = umn(v2, t1);
                }
                #pragma unroll
                for (int off = 16; off <= 32; off <<= 1) {
                    unsigned o1 = (unsigned)__shfl_xor((int)v1, off);
                    unsigned o2 = (unsigned)__shfl_xor((int)v2, off);
                    unsigned mx = umx(v1, o1);
                    v1 = umn(v1, o1);
                    v2 = umn(umn(v2, o2), mx);
                }
                int col = tile * 64 + ntp * 32 + n * 16 + (lane & 15);
                if (lane < 16 && col < NQ)
                    cand[(size_t)(wg * 8 + v) * QPAD + col] = make_uint2(v1, v2);
            }
        }
        asm volatile("s_waitcnt vmcnt(0)" ::: "memory");
        __syncthreads();
    }
#undef STAGE
}

// One wave per query row (4 waves/WG), zero barriers: per-lane streaming
// top-6 over 64 packed values -> 16 ballot-min extractions -> wave-parallel
// exact fp64 rescore -> top-4 -> neighbor mean.
__global__ __launch_bounds__(256) void merge_kernel(
    const float* __restrict__ query, const float* __restrict__ bank,
    const uint2* __restrict__ cand, float* __restrict__ nm)
{
    const int row = blockIdx.x * 4 + (threadIdx.x >> 6);
    const int lane = threadIdx.x & 63;

    unsigned s0 = 0xFFFFFFFFu, s1 = 0xFFFFFFFFu, s2 = 0xFFFFFFFFu;
    unsigned s3 = 0xFFFFFFFFu, s4 = 0xFFFFFFFFu, s5 = 0xFFFFFFFFu;

#define INSERT(uu)                                  \
    do {                                            \
        unsigned tt = (uu), nv;                     \
        nv = umn(s0, tt); tt = umx(s0, tt); s0 = nv;\
        nv = umn(s1, tt); tt = umx(s1, tt); s1 = nv;\
        nv = umn(s2, tt); tt = umx(s2, tt); s2 = nv;\
        nv = umn(s3, tt); tt = umx(s3, tt); s3 = nv;\
        nv = umn(s4, tt); tt = umx(s4, tt); s4 = nv;\
        s5 = umn(s5, tt);                           \
    } while (0)

    // lane owns groups [lane*32, lane*32+32); re-encode j into bits 5..9
    #pragma unroll 4
    for (int j = 0; j < 32; ++j) {
        uint2 e = cand[((size_t)(lane * 32 + j)) * QPAD + row];
        unsigned jb = (unsigned)(j << 5);
        unsigned u0 = (e.x & ~0x3E0u) | jb;
        unsigned u1 = (e.y & ~0x3E0u) | jb;
        INSERT(u0);
        INSERT(u1);
    }
#undef INSERT

    int cidx[RESCORE];
    #pragma unroll
    for (int it = 0; it < RESCORE; ++it) {
        unsigned gm = s0;
        #pragma unroll
        for (int off = 1; off < 64; off <<= 1)
            gm = umn(gm, (unsigned)__shfl_xor((int)gm, off));
        unsigned long long bal = __ballot(s0 == gm);
        int wl = __ffsll((long long)bal) - 1;
        if (lane == wl) { s0 = s1; s1 = s2; s2 = s3; s3 = s4; s4 = s5; s5 = 0xFFFFFFFFu; }
        int g = wl * 32 + (int)((gm >> 5) & 31u);
        cidx[it] = g * 32 + (int)(gm & 31u);
    }

    // ---- exact fp64 rescore, wave-parallel: lane covers 8 dims ----
    const float* qr = query + (size_t)row * DIMS + lane * 8;
    float4 qx = *(const float4*)qr;
    float4 qy = *(const float4*)(qr + 4);
    double d2[RESCORE];
    #pragma unroll
    for (int c = 0; c < RESCORE; ++c) {
        const float* mr = bank + (size_t)cidx[c] * DIMS + lane * 8;
        float4 mx = *(const float4*)mr;
        float4 my = *(const float4*)(mr + 4);
        double s = 0.0;
        double dd;
        dd = (double)qx.x - (double)mx.x; s += dd * dd;
        dd = (double)qx.y - (double)mx.y; s += dd * dd;
        dd = (double)qx.z - (double)mx.z; s += dd * dd;
        dd = (double)qx.w - (double)mx.w; s += dd * dd;
        dd = (double)qy.x - (double)my.x; s += dd * dd;
        dd = (double)qy.y - (double)my.y; s += dd * dd;
        dd = (double)qy.z - (double)my.z; s += dd * dd;
        dd = (double)qy.w - (double)my.w; s += dd * dd;
        #pragma unroll
        for (int off = 1; off < 64; off <<= 1) s += __shfl_xor(s, off);
        d2[c] = s;
    }

    // ---- top-4 of 16 (uniform across lanes), index tie-break ----
    int sel[4];
    unsigned used = 0;
    #pragma unroll
    for (int k = 0; k < 4; ++k) {
        double bv = 1e300; int bidx = 1 << 30; int bc = 0;
        #pragma unroll
        for (int c = 0; c < RESCORE; ++c) {
            bool live = !((used >> c) & 1u);
            if (live && (d2[c] < bv || (d2[c] == bv && cidx[c] < bidx))) {
                bv = d2[c]; bidx = cidx[c]; bc = c;
            }
        }
        used |= 1u << bc;
        sel[k] = bidx;
    }

    // ---- neighbor mean ----
    const float* r0 = bank + (size_t)sel[0] * DIMS + lane * 8;
    const float* r1 = bank + (size_t)sel[1] * DIMS + lane * 8;
    const float* r2 = bank + (size_t)sel[2] * DIMS + lane * 8;
    const float* r3 = bank + (size_t)sel[3] * DIMS + lane * 8;
    float* dst = nm + (size_t)row * DIMS + lane * 8;
    #pragma unroll
    for (int h = 0; h < 2; ++h) {
        float4 a = *(const float4*)(r0 + h * 4);
        float4 b = *(const float4*)(r1 + h * 4);
        float4 c = *(const float4*)(r2 + h * 4);
        float4 d = *(const float4*)(r3 + h * 4);
        float4 o;
        o.x = 0.25f * (a.x + b.x + c.x + d.x);
        o.y = 0.25f * (a.y + b.y + c.y + d.y);
        o.z = 0.25f * (a.z + b.z + c.z + d.z);
        o.w = 0.25f * (a.w + b.w + c.w + d.w);
        *(float4*)(dst + h * 4) = o;
    }
}

__global__ __launch_bounds__(256) void conv_kernel(
    const float* __restrict__ query, const float* __restrict__ nm,
    const float* __restrict__ fw, const float* __restrict__ fb,
    float* __restrict__ out)
{
    __shared__ float red[256];
    int pix = blockIdx.x, t = threadIdx.x;
    int i = pix / 28, j = pix % 28;
    float acc = 0.f;
    for (int c = t; c < 1024; c += 256) {
        const float* wrow = fw + c * 9;
        for (int di = 0; di < 3; ++di) {
            int h = i + di - 1;
            if (h < 0 || h >= 28) continue;
            for (int dj = 0; dj < 3; ++dj) {
                int w = j + dj - 1;
                if (w < 0 || w >= 28) continue;
                int n = h * 28 + w;
                float x = (c < 512) ? query[(size_t)n * 512 + c]
                                    : nm[(size_t)n * 512 + (c - 512)];
                acc += x * wrow[di * 3 + dj];
            }
        }
    }
    red[t] = acc;
    __syncthreads();
    for (int s = 128; s; s >>= 1) {
        if (t < s) red[t] += red[t + s];
        __syncthreads();
    }
    if (t == 0) out[pix] = red[0] + fb[0];
}

extern "C" void kernel_launch(void* const* d_in, const int* in_sizes, int n_in,
                              void* d_out, int out_size, void* d_ws, size_t ws_size,
                              hipStream_t stream)
{
    const float* query = (const float*)d_in[0];
    const float* bank  = (const float*)d_in[1];
    const float* fw    = (const float*)d_in[2];
    const float* fb    = (const float*)d_in[3];
    float* out = (float*)d_out;

    char* ws = (char*)d_ws;
    unsigned short* qbuf = (unsigned short*)ws;            // 832*512*2    =   851968 B
    uint2* cand = (uint2*)(ws + 851968);                   // 2048*832*8   = 13631488 B
    float* nm   = (float*)(ws + 851968 + 13631488);        // 784*512*4    =  1605632 B

    prep_query<<<QPAD * DIMS / 1024, 256, 0, stream>>>(query, qbuf);
    score_kernel<<<256, 512, 0, stream>>>(bank, qbuf, cand);
    merge_kernel<<<NQ / 4, 256, 0, stream>>>(query, bank, cand, nm);
    conv_kernel<<<NQ, 256, 0, stream>>>(query, nm, fw, fb, out);
}

// Round 5
// 126.919 us; speedup vs baseline: 5.6865x; 1.0135x over previous
//
#include <hip/hip_runtime.h>
#include <hip/hip_fp8.h>
#include <stdint.h>

#define DIMS 512
#define NQ 784
#define QPAD 832           // 13 tiles of 64 query columns
#define NTILE 13
#define RESCORE 32

typedef float f32x4 __attribute__((ext_vector_type(4)));

__device__ __forceinline__ unsigned umn(unsigned a, unsigned b) { return a < b ? a : b; }
__device__ __forceinline__ unsigned umx(unsigned a, unsigned b) { return a > b ? a : b; }

__device__ __forceinline__ unsigned pk4(float a, float b, float c, float d) {
#if __has_builtin(__builtin_amdgcn_cvt_pk_fp8_f32)
    int v = 0;
    v = __builtin_amdgcn_cvt_pk_fp8_f32(a, b, v, false);
    v = __builtin_amdgcn_cvt_pk_fp8_f32(c, d, v, true);
    return (unsigned)v;
#else
    __hip_fp8_e4m3 x(a), y(b), z(c), w(d);
    return (unsigned)x.__x | ((unsigned)y.__x << 8) | ((unsigned)z.__x << 16) | ((unsigned)w.__x << 24);
#endif
}

// fp32 query -> fp8 e4m3, XOR-swizzled within each column's 512B so the
// score kernel's ds_read_b64 pattern is bank-conflict-free with LINEAR
// global_load_lds staging. Padded cols (784..831) written as zeros.
__global__ __launch_bounds__(256) void prep_query(const float* __restrict__ q,
                                                  char* __restrict__ qb8) {
    int gid = blockIdx.x * 256 + threadIdx.x;   // 832 cols * 64 granules
    int col = gid >> 6;
    int k0 = (gid & 63) * 8;
    float4 a = make_float4(0.f, 0.f, 0.f, 0.f), b = a;
    if (col < NQ) {
        a = *(const float4*)(q + (size_t)col * DIMS + k0);
        b = *(const float4*)(q + (size_t)col * DIMS + k0 + 4);
    }
    uint2 o;
    o.x = pk4(a.x, a.y, a.z, a.w);
    o.y = pk4(b.x, b.y, b.z, b.w);
    *(uint2*)(qb8 + col * 512 + (k0 ^ ((col & 7) << 3))) = o;
}

// 512 WGs x 4 waves (2 WGs/CU). Each wave holds 32 bank rows (full K=512)
// as fp8 MFMA A-fragments in registers (64 VGPR). Query tiles (64 cols,
// fp8, swizzled) stream through double-buffered LDS via global_load_lds.
// All B addressing = 2 base VGPRs + compile-time ds offsets (tile-pair
// unroll). In-register top-2 per (col, 32-row group), exact rescore later.
__global__ __launch_bounds__(256, 2) void score_kernel(
    const float* __restrict__ bank,
    const char* __restrict__ qb8,
    uint2* __restrict__ cand)
{
    __shared__ __align__(16) char bt[2][64 * 512];   // 65536 B
    __shared__ float m2s[128];

    const int wg = blockIdx.x;        // owns rows wg*128 .. +128
    const int t = threadIdx.x;
    const int v = t >> 6;             // wave 0..3
    const int lane = t & 63;
    const int lo = lane & 15;
    const int kg = lane >> 4;         // 0..3

#define STAGE(BUF, TILE)                                                              \
    do {                                                                              \
        _Pragma("unroll")                                                             \
        for (int j = 0; j < 8; ++j) {                                                 \
            const int col = v * 16 + j * 2;                                           \
            const char* src = qb8 + ((size_t)((TILE) * 64 + col)) * 512 + lane * 16;  \
            __builtin_amdgcn_global_load_lds(                                         \
                (const __attribute__((address_space(1))) unsigned*)src,               \
                (__attribute__((address_space(3))) unsigned*)(&bt[BUF][col * 512]),   \
                16, 0, 0);                                                            \
        }                                                                             \
    } while (0)

    STAGE(0, 0);   // overlaps the A-load below

    // ---- A-load: 32 bank rows/wave, fp32 -> fp8 fragments + exact m2 ----
    long areg[2][16];
    float m2p[2];
    #pragma unroll
    for (int m = 0; m < 2; ++m) {
        const float* rp = bank + ((size_t)(wg * 128 + v * 32 + m * 16 + lo)) * DIMS + kg * 8;
        float ss = 0.f;
        #pragma unroll
        for (int ks = 0; ks < 16; ++ks) {
            float4 x = *(const float4*)(rp + ks * 32);
            float4 y = *(const float4*)(rp + ks * 32 + 4);
            ss += x.x * x.x + x.y * x.y + x.z * x.z + x.w * x.w;
            ss += y.x * y.x + y.y * y.y + y.z * y.z + y.w * y.w;
            unsigned l32 = pk4(x.x, x.y, x.z, x.w);
            unsigned h32 = pk4(y.x, y.y, y.z, y.w);
            areg[m][ks] = (long)(((unsigned long long)h32 << 32) | l32);
        }
        m2p[m] = ss;
    }
    #pragma unroll
    for (int m = 0; m < 2; ++m) {
        m2p[m] += __shfl_xor(m2p[m], 16);
        m2p[m] += __shfl_xor(m2p[m], 32);
    }
    if (lane < 16) {
        m2s[v * 32 + lane] = m2p[0];
        m2s[v * 32 + 16 + lane] = m2p[1];
    }

    asm volatile("s_waitcnt vmcnt(0)" ::: "memory");
    __syncthreads();

    // acc seed: -(512 + m2/2); packed score = -acc > 0 always
    f32x4 seed0, seed1;
    #pragma unroll
    for (int j = 0; j < 4; ++j) {
        seed0[j] = -(512.0f + 0.5f * m2s[v * 32 + kg * 4 + j]);
        seed1[j] = -(512.0f + 0.5f * m2s[v * 32 + 16 + kg * 4 + j]);
    }

    // B base pointers: swizzle folds into 2 bases; everything else is imm
    const char* pA0 = &bt[0][0] + lo * 512 + ((kg * 8) ^ ((lo & 7) << 3));
    const char* pA1 = (const char*)((uintptr_t)pA0 ^ 32);

#define KSLOOP(ACC, BUF, NTP)                                                              \
    do {                                                                                   \
        __builtin_amdgcn_s_setprio(1);                                                     \
        _Pragma("unroll")                                                                  \
        for (int ks = 0; ks < 16; ++ks) {                                                  \
            const char* bs = (ks & 1) ? pA1 : pA0;                                         \
            const int off = (BUF) * 32768 + (NTP) * 16384 + (ks >> 1) * 64;                \
            long b0 = *(const long*)(bs + off);                                            \
            long b1 = *(const long*)(bs + off + 8192);                                     \
            ACC[0][0] = __builtin_amdgcn_mfma_f32_16x16x32_fp8_fp8(areg[0][ks], b0, ACC[0][0], 0, 0, 0); \
            ACC[1][0] = __builtin_amdgcn_mfma_f32_16x16x32_fp8_fp8(areg[1][ks], b0, ACC[1][0], 0, 0, 0); \
            ACC[0][1] = __builtin_amdgcn_mfma_f32_16x16x32_fp8_fp8(areg[0][ks], b1, ACC[0][1], 0, 0, 0); \
            ACC[1][1] = __builtin_amdgcn_mfma_f32_16x16x32_fp8_fp8(areg[1][ks], b1, ACC[1][1], 0, 0, 0); \
        }                                                                                  \
        __builtin_amdgcn_s_setprio(0);                                                     \
    } while (0)

#define SEL(ACC, TILE, NTP)                                                                \
    do {                                                                                   \
        _Pragma("unroll")                                                                  \
        for (int n = 0; n < 2; ++n) {                                                      \
            unsigned v1 = 0xFFFFFFFFu, v2 = 0xFFFFFFFFu;                                   \
            _Pragma("unroll")                                                              \
            for (int m = 0; m < 2; ++m)                                                    \
                _Pragma("unroll")                                                          \
                for (int j = 0; j < 4; ++j) {                                              \
                    unsigned u = ((__float_as_uint(ACC[m][n][j]) ^ 0x80000000u) & ~31u)    \
                                 | (unsigned)(m * 16 + kg * 4 + j);                        \
                    unsigned mx = umx(v1, u);                                              \
                    v1 = umn(v1, u);                                                       \
                    v2 = umn(v2, mx);                                                      \
                }                                                                          \
            _Pragma("unroll")                                                              \
            for (int off = 16; off <= 32; off <<= 1) {                                     \
                unsigned o1 = (unsigned)__shfl_xor((int)v1, off);                          \
                unsigned o2 = (unsigned)__shfl_xor((int)v2, off);                          \
                unsigned mx = umx(v1, o1);                                                 \
                v1 = umn(v1, o1);                                                          \
                v2 = umn(umn(v2, o2), mx);                                                 \
            }                                                                              \
            int col = (TILE) * 64 + (NTP) * 32 + n * 16 + lo;                              \
            if (lane < 16 && col < NQ)                                                     \
                cand[(size_t)(wg * 4 + v) * QPAD + col] = make_uint2(v1, v2);              \
        }                                                                                  \
    } while (0)

#define TILEBODY(TILE, BUF)                                                                \
    do {                                                                                   \
        if ((TILE) + 1 < NTILE) STAGE((BUF) ^ 1, (TILE) + 1);                              \
        f32x4 accP[2][2], accQ[2][2];                                                      \
        accP[0][0] = seed0; accP[0][1] = seed0; accP[1][0] = seed1; accP[1][1] = seed1;    \
        KSLOOP(accP, BUF, 0);                                                              \
        accQ[0][0] = seed0; accQ[0][1] = seed0; accQ[1][0] = seed1; accQ[1][1] = seed1;    \
        KSLOOP(accQ, BUF, 1);                                                              \
        SEL(accP, TILE, 0);                                                                \
        SEL(accQ, TILE, 1);                                                                \
        asm volatile("s_waitcnt vmcnt(0)" ::: "memory");                                   \
        __syncthreads();                                                                   \
    } while (0)

    #pragma unroll 1
    for (int tt = 0; tt < 6; ++tt) {
        TILEBODY(2 * tt, 0);
        TILEBODY(2 * tt + 1, 1);
    }
    TILEBODY(12, 0);

#undef TILEBODY
#undef SEL
#undef KSLOOP
#undef STAGE
}

// One wave per query row, zero lockstep: per-lane sorted top-8 over 64
// packed values -> 32 ballot-min extractions -> exact fp64 rescore
// (2 lanes per candidate) -> top-4 -> neighbor mean.
__global__ __launch_bounds__(256) void merge_kernel(
    const float* __restrict__ query, const float* __restrict__ bank,
    const uint2* __restrict__ cand, float* __restrict__ nm)
{
    __shared__ double d2s[4][32];
    __shared__ int    cis[4][32];

    const int wv = threadIdx.x >> 6, lane = threadIdx.x & 63;
    const int row = blockIdx.x * 4 + wv;

    unsigned s0 = ~0u, s1 = ~0u, s2 = ~0u, s3 = ~0u;
    unsigned s4 = ~0u, s5 = ~0u, s6 = ~0u, s7 = ~0u;

#define INS(U)                                        \
    do {                                              \
        unsigned tt = (U), nv;                        \
        nv = umn(s0, tt); tt = umx(s0, tt); s0 = nv;  \
        nv = umn(s1, tt); tt = umx(s1, tt); s1 = nv;  \
        nv = umn(s2, tt); tt = umx(s2, tt); s2 = nv;  \
        nv = umn(s3, tt); tt = umx(s3, tt); s3 = nv;  \
        nv = umn(s4, tt); tt = umx(s4, tt); s4 = nv;  \
        nv = umn(s5, tt); tt = umx(s5, tt); s5 = nv;  \
        nv = umn(s6, tt); tt = umx(s6, tt); s6 = nv;  \
        s7 = umn(s7, tt);                             \
    } while (0)

    // lane owns groups [lane*32, +32); re-encode group-in-lane into bits 5..9
    #pragma unroll 4
    for (int j = 0; j < 32; ++j) {
        uint2 e = cand[((size_t)(lane * 32 + j)) * QPAD + row];
        unsigned jb = (unsigned)(j << 5);
        INS((e.x & ~0x3E0u) | jb);
        INS((e.y & ~0x3E0u) | jb);
    }
#undef INS

    const int myC = lane & 31;
    int myCand = 0;
    #pragma unroll
    for (int it = 0; it < RESCORE; ++it) {
        unsigned gm = s0;
        #pragma unroll
        for (int off = 1; off < 64; off <<= 1)
            gm = umn(gm, (unsigned)__shfl_xor((int)gm, off));
        unsigned long long bal = __ballot(s0 == gm);
        int wl = __ffsll((long long)bal) - 1;
        int ci = (wl * 32 + (int)((gm >> 5) & 31u)) * 32 + (int)(gm & 31u);
        myCand = (it == myC) ? ci : myCand;
        if (lane == wl) { s0 = s1; s1 = s2; s2 = s3; s3 = s4; s4 = s5; s5 = s6; s6 = s7; s7 = ~0u; }
    }

    // exact fp64 rescore: lanes l and l+32 split candidate (lane&31)'s dims
    const float* qr = query + (size_t)row * DIMS + (lane >> 5) * 256;
    const float* mr = bank + (size_t)myCand * DIMS + (lane >> 5) * 256;
    double s = 0.0;
    #pragma unroll 8
    for (int i = 0; i < 64; ++i) {
        float4 a = *(const float4*)(qr + i * 4);
        float4 b = *(const float4*)(mr + i * 4);
        double d;
        d = (double)a.x - (double)b.x; s += d * d;
        d = (double)a.y - (double)b.y; s += d * d;
        d = (double)a.z - (double)b.z; s += d * d;
        d = (double)a.w - (double)b.w; s += d * d;
    }
    s += __shfl_xor(s, 32);
    if (lane < 32) { d2s[wv][lane] = s; cis[wv][lane] = myCand; }
    __syncthreads();

    // top-4 of 32 (computed redundantly per lane), index tie-break
    int sel0 = 0, sel1 = 0, sel2 = 0, sel3 = 0;
    unsigned used = 0;
    #pragma unroll
    for (int k = 0; k < 4; ++k) {
        double bv = 1e300; int bidx = 0x7FFFFFFF; int bc = 0;
        for (int c = 0; c < 32; ++c) {
            bool live = !((used >> c) & 1u);
            double dv = d2s[wv][c];
            int cv = cis[wv][c];
            if (live && (dv < bv || (dv == bv && cv < bidx))) { bv = dv; bidx = cv; bc = c; }
        }
        used |= 1u << bc;
        if (k == 0) sel0 = bidx; else if (k == 1) sel1 = bidx;
        else if (k == 2) sel2 = bidx; else sel3 = bidx;
    }

    const float* r0 = bank + (size_t)sel0 * DIMS + lane * 8;
    const float* r1 = bank + (size_t)sel1 * DIMS + lane * 8;
    const float* r2 = bank + (size_t)sel2 * DIMS + lane * 8;
    const float* r3 = bank + (size_t)sel3 * DIMS + lane * 8;
    float* dst = nm + (size_t)row * DIMS + lane * 8;
    #pragma unroll
    for (int h = 0; h < 2; ++h) {
        float4 a = *(const float4*)(r0 + h * 4);
        float4 b = *(const float4*)(r1 + h * 4);
        float4 c = *(const float4*)(r2 + h * 4);
        float4 d = *(const float4*)(r3 + h * 4);
        float4 o;
        o.x = 0.25f * (a.x + b.x + c.x + d.x);
        o.y = 0.25f * (a.y + b.y + c.y + d.y);
        o.z = 0.25f * (a.z + b.z + c.z + d.z);
        o.w = 0.25f * (a.w + b.w + c.w + d.w);
        *(float4*)(dst + h * 4) = o;
    }
}

__global__ __launch_bounds__(256) void conv_kernel(
    const float* __restrict__ query, const float* __restrict__ nm,
    const float* __restrict__ fw, const float* __restrict__ fb,
    float* __restrict__ out)
{
    __shared__ float red[256];
    int pix = blockIdx.x, t = threadIdx.x;
    int i = pix / 28, j = pix % 28;
    float acc = 0.f;
    for (int c = t; c < 1024; c += 256) {
        const float* wrow = fw + c * 9;
        for (int di = 0; di < 3; ++di) {
            int h = i + di - 1;
            if (h < 0 || h >= 28) continue;
            for (int dj = 0; dj < 3; ++dj) {
                int w = j + dj - 1;
                if (w < 0 || w >= 28) continue;
                int n = h * 28 + w;
                float x = (c < 512) ? query[(size_t)n * 512 + c]
                                    : nm[(size_t)n * 512 + (c - 512)];
                acc += x * wrow[di * 3 + dj];
            }
        }
    }
    red[t] = acc;
    __syncthreads();
    for (int s = 128; s; s >>= 1) {
        if (t < s) red[t] += red[t + s];
        __syncthreads();
    }
    if (t == 0) out[pix] = red[0] + fb[0];
}

extern "C" void kernel_launch(void* const* d_in, const int* in_sizes, int n_in,
                              void* d_out, int out_size, void* d_ws, size_t ws_size,
                              hipStream_t stream)
{
    const float* query = (const float*)d_in[0];
    const float* bank  = (const float*)d_in[1];
    const float* fw    = (const float*)d_in[2];
    const float* fb    = (const float*)d_in[3];
    float* out = (float*)d_out;

    char* ws = (char*)d_ws;
    char*  qb8  = ws;                                      // 832*512      =   425984 B
    uint2* cand = (uint2*)(ws + 425984);                   // 2048*832*8   = 13631488 B
    float* nm   = (float*)(ws + 425984 + 13631488);        // 784*512*4    =  1605632 B

    prep_query<<<208, 256, 0, stream>>>(query, qb8);
    score_kernel<<<512, 256, 0, stream>>>(bank, qb8, cand);
    merge_kernel<<<NQ / 4, 256, 0, stream>>>(query, bank, cand, nm);
    conv_kernel<<<NQ, 256, 0, stream>>>(query, nm, fw, fb, out);
}

// Round 6
// 118.339 us; speedup vs baseline: 6.0988x; 1.0725x over previous
//
#include <hip/hip_runtime.h>
#include <hip/hip_fp8.h>
#include <stdint.h>

#define DIMS 512
#define NQ 784
#define QPAD 832           // 13 tiles of 64 query columns
#define NTILE 13
#define RESCORE 32
#define CSTR 528           // LDS/qb8p bytes per query column (512 + 16 pad)
#define TBYTES (64 * CSTR) // 33792 per tile image

typedef float f32x4 __attribute__((ext_vector_type(4)));
typedef long  l2v  __attribute__((ext_vector_type(2)));

__device__ __forceinline__ unsigned umn(unsigned a, unsigned b) { return a < b ? a : b; }
__device__ __forceinline__ unsigned umx(unsigned a, unsigned b) { return a > b ? a : b; }

__device__ __forceinline__ unsigned pk4(float a, float b, float c, float d) {
#if __has_builtin(__builtin_amdgcn_cvt_pk_fp8_f32)
    int v = 0;
    v = __builtin_amdgcn_cvt_pk_fp8_f32(a, b, v, false);
    v = __builtin_amdgcn_cvt_pk_fp8_f32(c, d, v, true);
    return (unsigned)v;
#else
    __hip_fp8_e4m3 x(a), y(b), z(c), w(d);
    return (unsigned)x.__x | ((unsigned)y.__x << 8) | ((unsigned)z.__x << 16) | ((unsigned)w.__x << 24);
#endif
}

// fp32 query -> fp8 e4m3 written as the exact LDS tile image:
// tile-major, column stride 528B, granule (8 dims) at kg*128 + ks*8
// (k = ks*32 + kg*8). Staging is then LINEAR global_load_lds and the
// score kernel's ds_read_b128 is capacity-optimal (no bank excess).
__global__ __launch_bounds__(256) void prep_query(const float* __restrict__ q,
                                                  char* __restrict__ qb8p) {
    int gid = blockIdx.x * 256 + threadIdx.x;   // 832 cols * 64 granules
    int col = gid >> 6;
    int g = gid & 63;                           // ks = g>>2, kg = g&3
    float4 a = make_float4(0.f, 0.f, 0.f, 0.f), b = a;
    if (col < NQ) {
        a = *(const float4*)(q + (size_t)col * DIMS + g * 8);
        b = *(const float4*)(q + (size_t)col * DIMS + g * 8 + 4);
    }
    uint2 o;
    o.x = pk4(a.x, a.y, a.z, a.w);
    o.y = pk4(b.x, b.y, b.z, b.w);
    int tile = col >> 6, cin = col & 63;
    *(uint2*)(qb8p + (size_t)tile * TBYTES + cin * CSTR + (g & 3) * 128 + (g >> 2) * 8) = o;
}

// 512 WGs x 4 waves (2 WGs/CU). Each wave holds 32 bank rows (full K=512)
// as fp8 MFMA A-fragments in registers. Query tiles stream through
// double-buffered LDS via linear global_load_lds of the padded image.
// B reads are ds_read_b128 (2 k-slices), all-immediate offsets.
__global__ __launch_bounds__(256, 2) void score_kernel(
    const float* __restrict__ bank,
    const char* __restrict__ qb8p,
    uint2* __restrict__ cand)
{
    __shared__ __align__(16) char bt[2][TBYTES];   // 67584 B
    __shared__ float m2s[128];

    const int wg = blockIdx.x;        // owns rows wg*128 .. +128
    const int t = threadIdx.x;
    const int v = t >> 6;             // wave 0..3
    const int lane = t & 63;
    const int lo = lane & 15;
    const int kg = lane >> 4;         // 0..3

#define STAGE(BUF, TILE)                                                              \
    do {                                                                              \
        _Pragma("unroll")                                                             \
        for (int j = 0; j < 8; ++j) {                                                 \
            const int ch = v * 8 + j;                                                 \
            const char* src = qb8p + (size_t)(TILE) * TBYTES + ch * 1024 + lane * 16; \
            __builtin_amdgcn_global_load_lds(                                         \
                (const __attribute__((address_space(1))) unsigned*)src,               \
                (__attribute__((address_space(3))) unsigned*)(&bt[BUF][ch * 1024]),   \
                16, 0, 0);                                                            \
        }                                                                             \
        if (v == 0) {                                                                 \
            const char* src = qb8p + (size_t)(TILE) * TBYTES + 32768 + lane * 16;     \
            __builtin_amdgcn_global_load_lds(                                         \
                (const __attribute__((address_space(1))) unsigned*)src,               \
                (__attribute__((address_space(3))) unsigned*)(&bt[BUF][32768]),       \
                16, 0, 0);                                                            \
        }                                                                             \
    } while (0)

    STAGE(0, 0);   // overlaps the A-load below

    // ---- A-load: 32 bank rows/wave, fp32 -> fp8 fragments + exact m2 ----
    long areg[2][16];
    float m2p[2];
    #pragma unroll
    for (int m = 0; m < 2; ++m) {
        const float* rp = bank + ((size_t)(wg * 128 + v * 32 + m * 16 + lo)) * DIMS + kg * 8;
        float ss = 0.f;
        #pragma unroll
        for (int ks = 0; ks < 16; ++ks) {
            float4 x = *(const float4*)(rp + ks * 32);
            float4 y = *(const float4*)(rp + ks * 32 + 4);
            ss += x.x * x.x + x.y * x.y + x.z * x.z + x.w * x.w;
            ss += y.x * y.x + y.y * y.y + y.z * y.z + y.w * y.w;
            unsigned l32 = pk4(x.x, x.y, x.z, x.w);
            unsigned h32 = pk4(y.x, y.y, y.z, y.w);
            areg[m][ks] = (long)(((unsigned long long)h32 << 32) | l32);
        }
        m2p[m] = ss;
    }
    #pragma unroll
    for (int m = 0; m < 2; ++m) {
        m2p[m] += __shfl_xor(m2p[m], 16);
        m2p[m] += __shfl_xor(m2p[m], 32);
    }
    if (lane < 16) {
        m2s[v * 32 + lane] = m2p[0];
        m2s[v * 32 + 16 + lane] = m2p[1];
    }

    asm volatile("s_waitcnt vmcnt(0)" ::: "memory");
    __syncthreads();

    // acc seed: -(512 + m2/2); packed score = -acc > 0 always
    f32x4 seed0, seed1;
    #pragma unroll
    for (int j = 0; j < 4; ++j) {
        seed0[j] = -(512.0f + 0.5f * m2s[v * 32 + kg * 4 + j]);
        seed1[j] = -(512.0f + 0.5f * m2s[v * 32 + 16 + kg * 4 + j]);
    }

    // single B base; all tile/buf/ntp/ks offsets are compile-time immediates
    const char* pB = &bt[0][0] + lo * CSTR + kg * 128;

#define KSLOOP(ACC, BUF, NTP)                                                              \
    do {                                                                                   \
        __builtin_amdgcn_s_setprio(1);                                                     \
        _Pragma("unroll")                                                                  \
        for (int ks2 = 0; ks2 < 8; ++ks2) {                                                \
            const int off = (BUF) * TBYTES + (NTP) * (32 * CSTR) + ks2 * 16;               \
            l2v B0 = *(const l2v*)(pB + off);                                              \
            l2v B1 = *(const l2v*)(pB + off + 16 * CSTR);                                  \
            ACC[0][0] = __builtin_amdgcn_mfma_f32_16x16x32_fp8_fp8(areg[0][2 * ks2], B0[0], ACC[0][0], 0, 0, 0); \
            ACC[1][0] = __builtin_amdgcn_mfma_f32_16x16x32_fp8_fp8(areg[1][2 * ks2], B0[0], ACC[1][0], 0, 0, 0); \
            ACC[0][1] = __builtin_amdgcn_mfma_f32_16x16x32_fp8_fp8(areg[0][2 * ks2], B1[0], ACC[0][1], 0, 0, 0); \
            ACC[1][1] = __builtin_amdgcn_mfma_f32_16x16x32_fp8_fp8(areg[1][2 * ks2], B1[0], ACC[1][1], 0, 0, 0); \
            ACC[0][0] = __builtin_amdgcn_mfma_f32_16x16x32_fp8_fp8(areg[0][2 * ks2 + 1], B0[1], ACC[0][0], 0, 0, 0); \
            ACC[1][0] = __builtin_amdgcn_mfma_f32_16x16x32_fp8_fp8(areg[1][2 * ks2 + 1], B0[1], ACC[1][0], 0, 0, 0); \
            ACC[0][1] = __builtin_amdgcn_mfma_f32_16x16x32_fp8_fp8(areg[0][2 * ks2 + 1], B1[1], ACC[0][1], 0, 0, 0); \
            ACC[1][1] = __builtin_amdgcn_mfma_f32_16x16x32_fp8_fp8(areg[1][2 * ks2 + 1], B1[1], ACC[1][1], 0, 0, 0); \
        }                                                                                  \
        __builtin_amdgcn_s_setprio(0);                                                     \
    } while (0)

#define SEL(ACC, TILE, NTP)                                                                \
    do {                                                                                   \
        _Pragma("unroll")                                                                  \
        for (int n = 0; n < 2; ++n) {                                                      \
            unsigned v1 = 0xFFFFFFFFu, v2 = 0xFFFFFFFFu;                                   \
            _Pragma("unroll")                                                              \
            for (int m = 0; m < 2; ++m)                                                    \
                _Pragma("unroll")                                                          \
                for (int j = 0; j < 4; ++j) {                                              \
                    unsigned u = ((__float_as_uint(ACC[m][n][j]) ^ 0x80000000u) & ~31u)    \
                                 | (unsigned)(m * 16 + kg * 4 + j);                        \
                    unsigned mx = umx(v1, u);                                              \
                    v1 = umn(v1, u);                                                       \
                    v2 = umn(v2, mx);                                                      \
                }                                                                          \
            _Pragma("unroll")                                                              \
            for (int off = 16; off <= 32; off <<= 1) {                                     \
                unsigned o1 = (unsigned)__shfl_xor((int)v1, off);                          \
                unsigned o2 = (unsigned)__shfl_xor((int)v2, off);                          \
                unsigned mx = umx(v1, o1);                                                 \
                v1 = umn(v1, o1);                                                          \
                v2 = umn(umn(v2, o2), mx);                                                 \
            }                                                                              \
            int col = (TILE) * 64 + (NTP) * 32 + n * 16 + lo;                              \
            if (lane < 16 && col < NQ)                                                     \
                cand[(size_t)(wg * 4 + v) * QPAD + col] = make_uint2(v1, v2);              \
        }                                                                                  \
    } while (0)

#define TILEBODY(TILE, BUF)                                                                \
    do {                                                                                   \
        if ((TILE) + 1 < NTILE) STAGE((BUF) ^ 1, (TILE) + 1);                              \
        f32x4 accP[2][2], accQ[2][2];                                                      \
        accP[0][0] = seed0; accP[0][1] = seed0; accP[1][0] = seed1; accP[1][1] = seed1;    \
        KSLOOP(accP, BUF, 0);                                                              \
        accQ[0][0] = seed0; accQ[0][1] = seed0; accQ[1][0] = seed1; accQ[1][1] = seed1;    \
        KSLOOP(accQ, BUF, 1);                                                              \
        SEL(accP, TILE, 0);                                                                \
        SEL(accQ, TILE, 1);                                                                \
        asm volatile("s_waitcnt vmcnt(0)" ::: "memory");                                   \
        __syncthreads();                                                                   \
    } while (0)

    #pragma unroll 1
    for (int tt = 0; tt < 6; ++tt) {
        TILEBODY(2 * tt, 0);
        TILEBODY(2 * tt + 1, 1);
    }
    TILEBODY(12, 0);

#undef TILEBODY
#undef SEL
#undef KSLOOP
#undef STAGE
}

// One wave per query row: per-lane sorted top-8 over 64 packed values ->
// 32 ballot-min extractions -> exact fp64 rescore (2 lanes/candidate) ->
// top-4 -> neighbor mean.
__global__ __launch_bounds__(256) void merge_kernel(
    const float* __restrict__ query, const float* __restrict__ bank,
    const uint2* __restrict__ cand, float* __restrict__ nm)
{
    __shared__ double d2s[4][32];
    __shared__ int    cis[4][32];

    const int wv = threadIdx.x >> 6, lane = threadIdx.x & 63;
    const int row = blockIdx.x * 4 + wv;

    unsigned s0 = ~0u, s1 = ~0u, s2 = ~0u, s3 = ~0u;
    unsigned s4 = ~0u, s5 = ~0u, s6 = ~0u, s7 = ~0u;

#define INS(U)                                        \
    do {                                              \
        unsigned tt = (U), nv;                        \
        nv = umn(s0, tt); tt = umx(s0, tt); s0 = nv;  \
        nv = umn(s1, tt); tt = umx(s1, tt); s1 = nv;  \
        nv = umn(s2, tt); tt = umx(s2, tt); s2 = nv;  \
        nv = umn(s3, tt); tt = umx(s3, tt); s3 = nv;  \
        nv = umn(s4, tt); tt = umx(s4, tt); s4 = nv;  \
        nv = umn(s5, tt); tt = umx(s5, tt); s5 = nv;  \
        nv = umn(s6, tt); tt = umx(s6, tt); s6 = nv;  \
        s7 = umn(s7, tt);                             \
    } while (0)

    // lane owns groups [lane*32, +32); re-encode group-in-lane into bits 5..9
    #pragma unroll 4
    for (int j = 0; j < 32; ++j) {
        uint2 e = cand[((size_t)(lane * 32 + j)) * QPAD + row];
        unsigned jb = (unsigned)(j << 5);
        INS((e.x & ~0x3E0u) | jb);
        INS((e.y & ~0x3E0u) | jb);
    }
#undef INS

    const int myC = lane & 31;
    int myCand = 0;
    #pragma unroll
    for (int it = 0; it < RESCORE; ++it) {
        unsigned gm = s0;
        #pragma unroll
        for (int off = 1; off < 64; off <<= 1)
            gm = umn(gm, (unsigned)__shfl_xor((int)gm, off));
        unsigned long long bal = __ballot(s0 == gm);
        int wl = __ffsll((long long)bal) - 1;
        int ci = (wl * 32 + (int)((gm >> 5) & 31u)) * 32 + (int)(gm & 31u);
        myCand = (it == myC) ? ci : myCand;
        if (lane == wl) { s0 = s1; s1 = s2; s2 = s3; s3 = s4; s4 = s5; s5 = s6; s6 = s7; s7 = ~0u; }
    }

    // exact fp64 rescore: lanes l and l+32 split candidate (lane&31)'s dims
    const float* qr = query + (size_t)row * DIMS + (lane >> 5) * 256;
    const float* mr = bank + (size_t)myCand * DIMS + (lane >> 5) * 256;
    double s = 0.0;
    #pragma unroll 8
    for (int i = 0; i < 64; ++i) {
        float4 a = *(const float4*)(qr + i * 4);
        float4 b = *(const float4*)(mr + i * 4);
        double d;
        d = (double)a.x - (double)b.x; s += d * d;
        d = (double)a.y - (double)b.y; s += d * d;
        d = (double)a.z - (double)b.z; s += d * d;
        d = (double)a.w - (double)b.w; s += d * d;
    }
    s += __shfl_xor(s, 32);
    if (lane < 32) { d2s[wv][lane] = s; cis[wv][lane] = myCand; }
    __syncthreads();

    // top-4 of 32 (computed redundantly per lane), index tie-break
    int sel0 = 0, sel1 = 0, sel2 = 0, sel3 = 0;
    unsigned used = 0;
    #pragma unroll
    for (int k = 0; k < 4; ++k) {
        double bv = 1e300; int bidx = 0x7FFFFFFF; int bc = 0;
        for (int c = 0; c < 32; ++c) {
            bool live = !((used >> c) & 1u);
            double dv = d2s[wv][c];
            int cv = cis[wv][c];
            if (live && (dv < bv || (dv == bv && cv < bidx))) { bv = dv; bidx = cv; bc = c; }
        }
        used |= 1u << bc;
        if (k == 0) sel0 = bidx; else if (k == 1) sel1 = bidx;
        else if (k == 2) sel2 = bidx; else sel3 = bidx;
    }

    const float* r0 = bank + (size_t)sel0 * DIMS + lane * 8;
    const float* r1 = bank + (size_t)sel1 * DIMS + lane * 8;
    const float* r2 = bank + (size_t)sel2 * DIMS + lane * 8;
    const float* r3 = bank + (size_t)sel3 * DIMS + lane * 8;
    float* dst = nm + (size_t)row * DIMS + lane * 8;
    #pragma unroll
    for (int h = 0; h < 2; ++h) {
        float4 a = *(const float4*)(r0 + h * 4);
        float4 b = *(const float4*)(r1 + h * 4);
        float4 c = *(const float4*)(r2 + h * 4);
        float4 d = *(const float4*)(r3 + h * 4);
        float4 o;
        o.x = 0.25f * (a.x + b.x + c.x + d.x);
        o.y = 0.25f * (a.y + b.y + c.y + d.y);
        o.z = 0.25f * (a.z + b.z + c.z + d.z);
        o.w = 0.25f * (a.w + b.w + c.w + d.w);
        *(float4*)(dst + h * 4) = o;
    }
}

__global__ __launch_bounds__(256) void conv_kernel(
    const float* __restrict__ query, const float* __restrict__ nm,
    const float* __restrict__ fw, const float* __restrict__ fb,
    float* __restrict__ out)
{
    __shared__ float red[256];
    int pix = blockIdx.x, t = threadIdx.x;
    int i = pix / 28, j = pix % 28;
    float acc = 0.f;
    for (int c = t; c < 1024; c += 256) {
        const float* wrow = fw + c * 9;
        for (int di = 0; di < 3; ++di) {
            int h = i + di - 1;
            if (h < 0 || h >= 28) continue;
            for (int dj = 0; dj < 3; ++dj) {
                int w = j + dj - 1;
                if (w < 0 || w >= 28) continue;
                int n = h * 28 + w;
                float x = (c < 512) ? query[(size_t)n * 512 + c]
                                    : nm[(size_t)n * 512 + (c - 512)];
                acc += x * wrow[di * 3 + dj];
            }
        }
    }
    red[t] = acc;
    __syncthreads();
    for (int s = 128; s; s >>= 1) {
        if (t < s) red[t] += red[t + s];
        __syncthreads();
    }
    if (t == 0) out[pix] = red[0] + fb[0];
}

extern "C" void kernel_launch(void* const* d_in, const int* in_sizes, int n_in,
                              void* d_out, int out_size, void* d_ws, size_t ws_size,
                              hipStream_t stream)
{
    const float* query = (const float*)d_in[0];
    const float* bank  = (const float*)d_in[1];
    const float* fw    = (const float*)d_in[2];
    const float* fb    = (const float*)d_in[3];
    float* out = (float*)d_out;

    char* ws = (char*)d_ws;
    char*  qb8p = ws;                                      // 13*33792     =   439296 B
    uint2* cand = (uint2*)(ws + 439296);                   // 2048*832*8   = 13631488 B
    float* nm   = (float*)(ws + 439296 + 13631488);        // 784*512*4    =  1605632 B

    prep_query<<<208, 256, 0, stream>>>(query, qb8p);
    score_kernel<<<512, 256, 0, stream>>>(bank, qb8p, cand);
    merge_kernel<<<NQ / 4, 256, 0, stream>>>(query, bank, cand, nm);
    conv_kernel<<<NQ, 256, 0, stream>>>(query, nm, fw, fb, out);
}